// Round 11
// baseline (59.207 us; speedup 1.0000x reference)
//
#include <hip/hip_runtime.h>
#include <cstdint>

// ---------------------------------------------------------------------------
// ObjectBoxDetect via bf16 MFMA. out[16,8400,85] fp32.
//   L0: x[16,256,80,80]  W[85,256]  stride 8   anchors [0,6400)
//   L1: x[16,512,40,40]  W[85,512]  stride 16  anchors [6400,8000)
//   L2: x[16,1024,20,20] W[85,1024] stride 32  anchors [8000,8400)
//
// Round-11: r6/r9/r10 all pin at 48.3us regardless of prefetch depth or
// barrier vmcnt semantics -> the barrier-per-kstep cadence itself is the
// clock (per-CU: ~1300cyc/block-kstep vs ~350cyc of issued work; convoyed
// waves). This round halves the cadence: BK=64 -- 2 ksteps of B per LDS
// buffer (12KB x2 = 24KB), ONE barrier per 2 ksteps, 12 MFMA + 12 ds_read
// + 16 A-loads per thread per period. A/B prefetch slack unchanged (~1
// period). Everything proven kept: heaviest-first grid, per-subtile b/hw0,
// launch_bounds(256,6) (r8 showed (256,8) spills).
// ---------------------------------------------------------------------------

typedef __attribute__((ext_vector_type(8))) short bf16x8;
typedef __attribute__((ext_vector_type(4))) float f32x4;

constexpr int KS0 = 8, KS1 = 16, KS2 = 32;            // K-steps per level (C/32)
constexpr int F0 = 6 * KS0, F1 = 6 * KS1, F2 = 6 * KS2;
constexpr int FOFF0 = 0, FOFF1 = F0, FOFF2 = F0 + F1;
constexpr int NFRAG = F0 + F1 + F2;                    // 336 fragments
constexpr size_t BIAS_OFF = 0;                         // 3*96 floats = 1152 B
constexpr size_t BPK_OFF  = 1152;                      // 16B aligned
constexpr size_t WS_NEED  = BPK_OFF + (size_t)NFRAG * 64 * 16;

__device__ __forceinline__ unsigned short f2bf(float f) {
    union { float f; unsigned u; } v; v.f = f;
    unsigned r = v.u + 0x7FFF + ((v.u >> 16) & 1);     // round-to-nearest-even
    return (unsigned short)(r >> 16);
}

// Barrier that does NOT drain vmcnt (LDS settled via lgkmcnt only).
__device__ __forceinline__ void barrier_keep_vmcnt() {
    asm volatile("s_waitcnt lgkmcnt(0)" ::: "memory");
    __builtin_amdgcn_s_barrier();
}

// Pack W[o][c] -> bf16 B-fragments ([ks][n]-major per level) + padded bias.
// B frag layout (16x16x32): lane l holds col o = n*16+(l&15),
// k-slots c = ks*32 + (l>>4)*8 + e.
__global__ __launch_bounds__(256) void prep_pack(
    const float* __restrict__ W0, const float* __restrict__ W1,
    const float* __restrict__ W2,
    const float* __restrict__ b0, const float* __restrict__ b1,
    const float* __restrict__ b2,
    unsigned char* __restrict__ ws)
{
    int t = blockIdx.x * 256 + threadIdx.x;
    if (t < 288) {
        int lvl = t / 96, o = t % 96;
        const float* bp = (lvl == 0) ? b0 : (lvl == 1) ? b1 : b2;
        ((float*)(ws + BIAS_OFF))[t] = (o < 85) ? bp[o] : 0.0f;
    }
    if (t >= NFRAG * 64) return;
    int frag = t >> 6, l = t & 63;
    int C; const float* W; int f;
    if (frag < FOFF1)      { C = 256;  W = W0; f = frag;         }
    else if (frag < FOFF2) { C = 512;  W = W1; f = frag - FOFF1; }
    else                   { C = 1024; W = W2; f = frag - FOFF2; }
    int ks = f / 6, n = f % 6;                          // [ks][n]-major
    int o  = n * 16 + (l & 15);
    int c0 = ks * 32 + (l >> 4) * 8;
    bf16x8 r;
#pragma unroll
    for (int e = 0; e < 8; ++e)
        r[e] = (o < 85) ? (short)f2bf(W[(size_t)o * C + c0 + e]) : (short)0;
    ((bf16x8*)(ws + BPK_OFF))[frag * 64 + l] = r;
}

template <int C, int HW, int NX, int LEVEL, int AOFF, int KSTEPS, int FOFF>
__device__ __forceinline__ void mfma_level(
    const float* __restrict__ feat, const unsigned char* __restrict__ ws,
    float* __restrict__ out, int blk, uint4* __restrict__ Bsm /* [2][768] */)
{
    constexpr int NP = KSTEPS / 2;     // barrier periods (BK=64)
    const int tid = threadIdx.x;
    const int w   = tid >> 6;
    const int l   = tid & 63;
    const int col = l & 15;            // output col within 16-tile
    const int kg  = l >> 4;            // k-group

    // one 16-pos M-subtile per wave; HW % 16 == 0 so it stays in one batch.
    const int p0  = blk * 64 + w * 16;
    const int b   = p0 / HW;
    const int hw0 = p0 - b * HW;
    const float* fb = feat + (size_t)b * C * HW + hw0;
    const float* pA = fb + col + (size_t)(kg * 8) * HW;   // per-lane A base

    const float* bias = (const float*)(ws + BIAS_OFF) + LEVEL * 96;
    const uint4* bsrc = (const uint4*)(ws + BPK_OFF) + (size_t)FOFF * 64;

    f32x4 acc[6];
#pragma unroll
    for (int n = 0; n < 6; ++n) {
        float bv = bias[n * 16 + col];
        f32x4 z = { bv, bv, bv, bv };
        acc[n] = z;
    }

    uint4* bufc = Bsm;                 // consume buffer (12 KB = 768 uint4)
    uint4* bufn = Bsm + 768;           // stage buffer

    // ---- prologue ----
    // B(period 0) straight into bufc: 768 uint4 = 3/thread
    {
        const uint4* s = bsrc;
        bufc[tid]       = s[tid];
        bufc[256 + tid] = s[256 + tid];
        bufc[512 + tid] = s[512 + tid];
    }
    // A(0) -> flA0, A(1) -> flA1
    float flA0[8], flA1[8];
#pragma unroll
    for (int e = 0; e < 8; ++e) flA0[e] = pA[(size_t)e * HW];
    {
        const float* p = pA + (size_t)32 * HW;
#pragma unroll
        for (int e = 0; e < 8; ++e) flA1[e] = p[(size_t)e * HW];
    }
    // B(period 1) -> pend regs
    uint4 pb0, pb1, pb2;
    if (NP > 1) {
        const uint4* s = bsrc + 768;
        pb0 = s[tid];
        pb1 = s[256 + tid];
        pb2 = s[512 + tid];
    }
    barrier_keep_vmcnt();

#pragma unroll 1
    for (int p = 0; p < NP; ++p) {
        // 1. cvt A(2p), A(2p+1) -> fragments (loaded >= 1 period ago)
        bf16x8 a0, a1;
#pragma unroll
        for (int e = 0; e < 8; ++e) a0[e] = (short)f2bf(flA0[e]);
#pragma unroll
        for (int e = 0; e < 8; ++e) a1[e] = (short)f2bf(flA1[e]);

        // 2. issue next period's A loads (land during MFMA + barrier)
        if (p + 1 < NP) {
            const float* q0 = pA + (size_t)((2 * p + 2) * 32) * HW;
            const float* q1 = pA + (size_t)((2 * p + 3) * 32) * HW;
#pragma unroll
            for (int e = 0; e < 8; ++e) flA0[e] = q0[(size_t)e * HW];
#pragma unroll
            for (int e = 0; e < 8; ++e) flA1[e] = q1[(size_t)e * HW];
        }

        // 3. ds_write pend B(period p+1) -> bufn (issued a full period ago)
        if (p + 1 < NP) {
            bufn[tid]       = pb0;
            bufn[256 + tid] = pb1;
            bufn[512 + tid] = pb2;
        }
        // 4. issue B(period p+2) -> pend regs
        if (p + 2 < NP) {
            const uint4* s = bsrc + (size_t)(p + 2) * 768;
            pb0 = s[tid];
            pb1 = s[256 + tid];
            pb2 = s[512 + tid];
        }

        // 5. 12 MFMA from bufc: kstep 2p (first 384 uint4), 2p+1 (next 384)
        const bf16x8* bl0 = (const bf16x8*)bufc;
        const bf16x8* bl1 = (const bf16x8*)(bufc + 384);
#pragma unroll
        for (int n = 0; n < 6; ++n) {
            bf16x8 bq = bl0[n * 64 + l];
            acc[n] = __builtin_amdgcn_mfma_f32_16x16x32_bf16(a0, bq, acc[n], 0, 0, 0);
        }
#pragma unroll
        for (int n = 0; n < 6; ++n) {
            bf16x8 bq = bl1[n * 64 + l];
            acc[n] = __builtin_amdgcn_mfma_f32_16x16x32_bf16(a1, bq, acc[n], 0, 0, 0);
        }

        // 6. one barrier per period (2 ksteps)
        barrier_keep_vmcnt();
        uint4* t = bufc; bufc = bufn; bufn = t;
    }

    // Epilogue. C/D layout (m89-verified): col = l&15, row = (l>>4)*4 + j.
    constexpr float S  = (float)(8 << LEVEL);
    constexpr float P4 = 4.0f * (float)(1 << LEVEL);
#pragma unroll
    for (int j = 0; j < 4; ++j) {
        const int hw = hw0 + kg * 4 + j;
        float sg[6];
#pragma unroll
        for (int n = 0; n < 6; ++n) {
            float v = acc[n][j];
            sg[n] = __builtin_amdgcn_rcpf(1.0f + __expf(-v));
        }
        const int grp = l & 48;
        float y0 = __shfl(sg[0], grp + 0);
        float y1 = __shfl(sg[0], grp + 1);
        float y2 = __shfl(sg[0], grp + 2);
        float y3 = __shfl(sg[0], grp + 3);
        float wx = (float)(hw % NX);
        float wy = (float)(hw / NX);
        float d0 = y0 * y0 * P4, d1 = y1 * y1 * P4;
        float d2 = y2 * y2 * P4, d3 = y3 * y3 * P4;
        float x1 = (wx + 1.0f - d0) * S;
        float yA = (wy + 1.0f - d1) * S;
        float x2 = (wx + d2) * S;
        float yB = (wy + d3) * S;
        float bx = (x1 + x2) * 0.5f, by = (yA + yB) * 0.5f;
        float bw = x2 - x1,          bh = yB - yA;
        sg[0] = (col == 0) ? bx : (col == 1) ? by
              : (col == 2) ? bw : (col == 3) ? bh : sg[0];
        float* op = out + ((size_t)b * 8400 + AOFF + hw) * 85;
#pragma unroll
        for (int n = 0; n < 6; ++n) {
            int o = n * 16 + col;
            if (o < 85) op[o] = sg[n];
        }
    }
}

// Grid: 2100 blocks of 64 positions, heaviest-first (longest-job-first).
__global__ __launch_bounds__(256, 6) void detect_mfma(
    const float* __restrict__ x0, const float* __restrict__ x1,
    const float* __restrict__ x2,
    const unsigned char* __restrict__ ws, float* __restrict__ out)
{
    __shared__ uint4 Bsm[2 * 768];     // 24 KB double-buffered B stage (BK=64)
    int blk = blockIdx.x;
    if (blk < 100)      mfma_level<1024, 400,  20, 2, 8000, KS2, FOFF2>(x2, ws, out, blk,       Bsm);
    else if (blk < 500) mfma_level<512,  1600, 40, 1, 6400, KS1, FOFF1>(x1, ws, out, blk - 100, Bsm);
    else                mfma_level<256,  6400, 80, 0, 0,    KS0, FOFF0>(x0, ws, out, blk - 500, Bsm);
}

// ---------------- fallback (ws too small): round-2 VALU path ----------------
template <int C, int HW, int NX, int LEVEL, int ONUM, bool BOX>
__device__ __forceinline__ void decode_path_fb(
    const float* __restrict__ feat, const float* __restrict__ Wm,
    const float* __restrict__ bias, float* __restrict__ out,
    int o_lo_in, int pos)
{
    const int o_lo = __builtin_amdgcn_readfirstlane(o_lo_in);
    const int b  = pos / HW;
    const int hw = pos - b * HW;
    const float* fp = feat + (size_t)b * (C * HW) + hw;
    float acc[ONUM];
#pragma unroll
    for (int j = 0; j < ONUM; ++j) acc[j] = bias[o_lo + j];
#pragma unroll 4
    for (int c = 0; c < C; ++c) {
        float fv = fp[(size_t)c * HW];
#pragma unroll
        for (int j = 0; j < ONUM; ++j)
            acc[j] = fmaf(fv, Wm[(o_lo + j) * C + c], acc[j]);
    }
#pragma unroll
    for (int j = 0; j < ONUM; ++j)
        acc[j] = __builtin_amdgcn_rcpf(1.0f + __expf(-acc[j]));
    constexpr float S = (float)(8 << LEVEL);
    constexpr int AOFF = (LEVEL == 0) ? 0 : ((LEVEL == 1) ? 6400 : 8000);
    float* op = out + ((size_t)b * 8400 + AOFF + hw) * 85 + o_lo;
    if constexpr (BOX) {
        constexpr float P4 = 4.0f * (float)(1 << LEVEL);
        float wx = (float)(hw % NX), wy = (float)(hw / NX);
        float d0 = acc[0] * acc[0] * P4, d1 = acc[1] * acc[1] * P4;
        float d2 = acc[2] * acc[2] * P4, d3 = acc[3] * acc[3] * P4;
        float x1 = (wx + 1.0f - d0) * S, y1 = (wy + 1.0f - d1) * S;
        float x2 = (wx + d2) * S,        y2 = (wy + d3) * S;
        op[0] = (x1 + x2) * 0.5f; op[1] = (y1 + y2) * 0.5f;
        op[2] = x2 - x1;          op[3] = y2 - y1;
#pragma unroll
        for (int j = 4; j < ONUM; ++j) op[j] = acc[j];
    } else {
#pragma unroll
        for (int j = 0; j < ONUM; ++j) op[j] = acc[j];
    }
}

template <int C, int HW, int NX, int LEVEL>
__device__ __forceinline__ void level_block_fb(
    const float* __restrict__ feat, const float* __restrict__ Wm,
    const float* __restrict__ bias, float* __restrict__ out, int bb)
{
    const int wave = threadIdx.x >> 6, lane = threadIdx.x & 63;
    const int pos = bb * 64 + lane;
    if      (wave == 0) decode_path_fb<C, HW, NX, LEVEL, 22, true >(feat, Wm, bias, out, 0,  pos);
    else if (wave == 1) decode_path_fb<C, HW, NX, LEVEL, 22, false>(feat, Wm, bias, out, 22, pos);
    else if (wave == 2) decode_path_fb<C, HW, NX, LEVEL, 22, false>(feat, Wm, bias, out, 44, pos);
    else                decode_path_fb<C, HW, NX, LEVEL, 19, false>(feat, Wm, bias, out, 66, pos);
}

__global__ __launch_bounds__(256) void detect_fallback(
    const float* __restrict__ x0, const float* __restrict__ x1,
    const float* __restrict__ x2,
    const float* __restrict__ w0, const float* __restrict__ w1,
    const float* __restrict__ w2,
    const float* __restrict__ b0, const float* __restrict__ b1,
    const float* __restrict__ b2, float* __restrict__ out)
{
    const int blk = blockIdx.x;
    if (blk < 100)      level_block_fb<1024, 400,  20, 2>(x2, w2, b2, out, blk);
    else if (blk < 500) level_block_fb<512,  1600, 40, 1>(x1, w1, b1, out, blk - 100);
    else                level_block_fb<256,  6400, 80, 0>(x0, w0, b0, out, blk - 500);
}

extern "C" void kernel_launch(void* const* d_in, const int* in_sizes, int n_in,
                              void* d_out, int out_size, void* d_ws, size_t ws_size,
                              hipStream_t stream)
{
    const float* x0 = (const float*)d_in[0];
    const float* x1 = (const float*)d_in[1];
    const float* x2 = (const float*)d_in[2];
    const float* W0 = (const float*)d_in[3];
    const float* b0 = (const float*)d_in[4];
    const float* W1 = (const float*)d_in[5];
    const float* b1 = (const float*)d_in[6];
    const float* W2 = (const float*)d_in[7];
    const float* b2 = (const float*)d_in[8];
    float* out = (float*)d_out;

    if (ws_size >= WS_NEED) {
        unsigned char* ws = (unsigned char*)d_ws;
        prep_pack<<<(NFRAG * 64 + 255) / 256, 256, 0, stream>>>(W0, W1, W2, b0, b1, b2, ws);
        detect_mfma<<<2100, 256, 0, stream>>>(x0, x1, x2, ws, out);
    } else {
        detect_fallback<<<2100, 256, 0, stream>>>(x0, x1, x2, W0, W1, W2, b0, b1, b2, out);
    }
}